// Round 9
// baseline (386.557 us; speedup 1.0000x reference)
//
#include <hip/hip_runtime.h>

// ---- problem constants ----
constexpr int Bc   = 4;
constexpr int Qlen = 2048;
constexpr int Klen = 2048;
constexpr int Dm   = 512;
constexpr int Hh   = 8;
constexpr int HDim = 64;

typedef __attribute__((ext_vector_type(8))) short short8;       // 8x16-bit storage
typedef __attribute__((ext_vector_type(8))) _Float16 half8;     // fp16 MFMA frag
typedef __attribute__((ext_vector_type(2))) __fp16 fp16x2;      // cvt_pkrtz result
typedef __attribute__((ext_vector_type(4))) float f32x4;

__device__ __forceinline__ f32x4 MFMA16(short8 a, short8 b, f32x4 c) {
  return __builtin_amdgcn_mfma_f32_16x16x32_f16(
      __builtin_bit_cast(half8, a), __builtin_bit_cast(half8, b), c, 0, 0, 0);
}

__device__ __forceinline__ void gload_lds16(const void* g, void* l) {
  __builtin_amdgcn_global_load_lds(
      (const __attribute__((address_space(1))) void*)g,
      (__attribute__((address_space(3))) void*)l, 16, 0, 0);
}

__device__ __forceinline__ unsigned short f2h(float f) {   // f32 -> fp16 RNE
  _Float16 h = (_Float16)f;
  return __builtin_bit_cast(unsigned short, h);
}

__device__ __forceinline__ unsigned pk2h(float a, float b) {  // packed f32x2 -> f16x2
  fp16x2 h = __builtin_amdgcn_cvt_pkrtz(a, b);
  return __builtin_bit_cast(unsigned, h);
}

// ============================================================
// cvt4: f32->fp16 of the 4 weight matrices + mask->f32 bias (seg 4)
// ============================================================
__global__ __launch_bounds__(256) void cvt4(
    const float* __restrict__ s0, const float* __restrict__ s1,
    const float* __restrict__ s2, const float* __restrict__ s3,
    unsigned short* __restrict__ o0, unsigned short* __restrict__ o1,
    unsigned short* __restrict__ o2, unsigned short* __restrict__ o3,
    const int* __restrict__ msk, float* __restrict__ biasf) {
  const int seg = blockIdx.y;
  int i = (blockIdx.x * 256 + threadIdx.x) * 4;
  if (seg < 4) {
    const float* s = (seg == 0) ? s0 : (seg == 1) ? s1 : (seg == 2) ? s2 : s3;
    unsigned short* o = (seg == 0) ? o0 : (seg == 1) ? o1 : (seg == 2) ? o2 : o3;
    float4 x = *(const float4*)(s + i);
    unsigned t[2] = {pk2h(x.x, x.y), pk2h(x.z, x.w)};
    *(uint2*)(o + i) = *(const uint2*)t;
  } else if (i + 3 < Bc * Klen) {   // mask -> additive exp2-domain bias
    int4 m = *(const int4*)(msk + i);
    float4 bo;
    bo.x = (m.x == 0) ? -60000.0f : 0.0f;
    bo.y = (m.y == 0) ? -60000.0f : 0.0f;
    bo.z = (m.z == 0) ? -60000.0f : 0.0f;
    bo.w = (m.w == 0) ? -60000.0f : 0.0f;
    *(float4*)(biasf + i) = bo;
  }
}

// ============================================================
// cvt_in: f32->fp16 of the 3 input activations (B*Q*D each)
// ============================================================
__global__ __launch_bounds__(256) void cvt_in(
    const float* __restrict__ q, const float* __restrict__ k,
    const float* __restrict__ v,
    unsigned short* __restrict__ qh, unsigned short* __restrict__ kh,
    unsigned short* __restrict__ vh) {
  const int seg = blockIdx.y;
  const float* s = (seg == 0) ? q : (seg == 1) ? k : v;
  unsigned short* o = (seg == 0) ? qh : (seg == 1) ? kh : vh;
  int i = (blockIdx.x * 256 + threadIdx.x) * 4;
  float4 x = *(const float4*)(s + i);
  unsigned t[2] = {pk2h(x.x, x.y), pk2h(x.z, x.w)};
  *(uint2*)(o + i) = *(const uint2*)t;
}

// ============================================================
// Fused QKV projection: C[m,n] = X[m,:] . W[n,:]  (X @ W^T)
// F16A=true: A pre-converted fp16, global_load_lds both sides.
// F16A=false: fallback, f32 A converted in-flight.
// ============================================================
template <bool F16A>
__global__ __launch_bounds__(256) void gemm_qkv(
    const float* __restrict__ q_in,
    const float* __restrict__ k_in,
    const float* __restrict__ v_in,
    const unsigned short* __restrict__ qh,
    const unsigned short* __restrict__ kh,
    const unsigned short* __restrict__ vh,
    const unsigned short* __restrict__ Wqh,
    const unsigned short* __restrict__ Wkh,
    const unsigned short* __restrict__ Wvh,
    unsigned short* __restrict__ Qp,
    unsigned short* __restrict__ Kp,
    unsigned short* __restrict__ Vp) {
  __shared__ unsigned short As[128 * 32];
  __shared__ unsigned short Bs[128 * 32];
  const int tid = threadIdx.x;
  const int w = tid >> 6, l = tid & 63;
  const int quad = l >> 4, l15 = l & 15;
  const int m0 = blockIdx.x * 128;
  const int n0 = blockIdx.y * 128;
  const int seg = n0 >> 9;
  const int f0  = n0 & 511;
  const float* Af = (seg == 0) ? q_in : (seg == 1) ? k_in : v_in;
  const unsigned short* Ah = (seg == 0) ? qh : (seg == 1) ? kh : vh;
  const unsigned short* W = (seg == 0) ? Wqh : (seg == 1) ? Wkh : Wvh;
  unsigned short* dst = (seg == 0) ? Qp : (seg == 1) ? Kp : Vp;

  f32x4 acc[4][4] = {};
  const int lrow = l >> 2;
  const int lcol = (l & 3) * 8;
  const int wm = (w >> 1) * 64, wn = (w & 1) * 64;

  for (int kk = 0; kk < 512; kk += 32) {
#pragma unroll
    for (int i = 0; i < 2; ++i) {
      int row = w * 32 + i * 16 + lrow;
      if constexpr (F16A) {
        gload_lds16(Ah + (size_t)(m0 + row) * 512 + kk + lcol, &As[row * 32 + lcol]);
      } else {
        const float* ap = Af + (size_t)(m0 + row) * 512 + kk + lcol;
        float4 x0 = *(const float4*)(ap);
        float4 x1 = *(const float4*)(ap + 4);
        unsigned t[4] = {pk2h(x0.x, x0.y), pk2h(x0.z, x0.w),
                         pk2h(x1.x, x1.y), pk2h(x1.z, x1.w)};
        *(uint4*)&As[row * 32 + lcol] = *(const uint4*)t;
      }
      gload_lds16(W + (size_t)(f0 + row) * 512 + kk + lcol, &Bs[row * 32 + lcol]);
    }
    __syncthreads();
    short8 af[4], bf[4];
#pragma unroll
    for (int t = 0; t < 4; ++t)
      af[t] = *(const short8*)&As[(wm + t * 16 + l15) * 32 + quad * 8];
#pragma unroll
    for (int t = 0; t < 4; ++t)
      bf[t] = *(const short8*)&Bs[(wn + t * 16 + l15) * 32 + quad * 8];
#pragma unroll
    for (int mt = 0; mt < 4; ++mt)
#pragma unroll
      for (int nt = 0; nt < 4; ++nt)
        acc[mt][nt] = MFMA16(af[mt], bf[nt], acc[mt][nt]);
    __syncthreads();
  }
#pragma unroll
  for (int mt = 0; mt < 4; ++mt)
#pragma unroll
    for (int nt = 0; nt < 4; ++nt)
#pragma unroll
      for (int r = 0; r < 4; ++r) {
        int m  = m0 + wm + mt * 16 + quad * 4 + r;
        int nn = f0 + wn + nt * 16 + l15;
        int b = m >> 11, qq = m & 2047;
        int h = nn >> 6, hd = nn & 63;
        dst[(((size_t)(b * Hh + h)) * Qlen + qq) * HDim + hd] = f2h(acc[mt][nt][r]);
      }
}

// ============================================================
// V transpose: Vp (B,H,K,HD) -> Vt (B,H,HD,K), 64x64 tiles via LDS
// ============================================================
__global__ __launch_bounds__(256) void transpose_v(
    const unsigned short* __restrict__ Vp, unsigned short* __restrict__ Vt) {
  __shared__ unsigned short t[64 * 72];
  const int bh = blockIdx.y, jt = blockIdx.x;
  const int tid = threadIdx.x;
#pragma unroll
  for (int i = 0; i < 2; ++i) {
    int g = i * 256 + tid;
    int j = g >> 3, c8 = g & 7;
    *(uint4*)&t[j * 72 + c8 * 8] =
        *(const uint4*)(Vp + ((size_t)bh * Klen + jt * 64 + j) * 64 + c8 * 8);
  }
  __syncthreads();
#pragma unroll
  for (int i = 0; i < 2; ++i) {
    int g = i * 256 + tid;
    int d = g >> 3, j8 = g & 7;
    unsigned short tmp[8];
#pragma unroll
    for (int kx = 0; kx < 8; ++kx) tmp[kx] = t[(j8 * 8 + kx) * 72 + d];
    *(uint4*)(Vt + ((size_t)bh * HDim + d) * Klen + jt * 64 + j8 * 8) = *(const uint4*)tmp;
  }
}

// ============================================================
// Output projection: d_out[m,n] = Oa[m,:] . Wo[n,:], fp32 row-major out
// ============================================================
__global__ __launch_bounds__(256) void gemm_out(
    const unsigned short* __restrict__ Oa,
    const unsigned short* __restrict__ Woh,
    float* __restrict__ out) {
  __shared__ unsigned short As[128 * 32];
  __shared__ unsigned short Bs[128 * 32];
  const int tid = threadIdx.x;
  const int w = tid >> 6, l = tid & 63;
  const int quad = l >> 4, l15 = l & 15;
  const int m0 = blockIdx.x * 128;
  const int n0 = blockIdx.y * 128;

  f32x4 acc[4][4] = {};
  const int lrow = l >> 2;
  const int lcol = (l & 3) * 8;
  const int wm = (w >> 1) * 64, wn = (w & 1) * 64;

  for (int kk = 0; kk < 512; kk += 32) {
#pragma unroll
    for (int i = 0; i < 2; ++i) {
      int row = w * 32 + i * 16 + lrow;
      gload_lds16(Oa + (size_t)(m0 + row) * 512 + kk + lcol, &As[row * 32 + lcol]);
      gload_lds16(Woh + (size_t)(n0 + row) * 512 + kk + lcol, &Bs[row * 32 + lcol]);
    }
    __syncthreads();
    short8 af[4], bf[4];
#pragma unroll
    for (int t = 0; t < 4; ++t)
      af[t] = *(const short8*)&As[(wm + t * 16 + l15) * 32 + quad * 8];
#pragma unroll
    for (int t = 0; t < 4; ++t)
      bf[t] = *(const short8*)&Bs[(wn + t * 16 + l15) * 32 + quad * 8];
#pragma unroll
    for (int mt = 0; mt < 4; ++mt)
#pragma unroll
      for (int nt = 0; nt < 4; ++nt)
        acc[mt][nt] = MFMA16(af[mt], bf[nt], acc[mt][nt]);
    __syncthreads();
  }
#pragma unroll
  for (int mt = 0; mt < 4; ++mt)
#pragma unroll
    for (int nt = 0; nt < 4; ++nt)
#pragma unroll
      for (int r = 0; r < 4; ++r) {
        int m  = m0 + wm + mt * 16 + quad * 4 + r;
        int nn = n0 + wn + nt * 16 + l15;
        out[(size_t)m * 512 + nn] = acc[mt][nt][r];
      }
}

// ============================================================
// Flash attention v5: BARRIER-FREE K-loop.
// K/V MFMA fragments loaded directly from global into registers
// (L2/L3-resident; 4 waves/block share tiles via L1). K prefetched
// one tile ahead; V issued at tile top, consumed after softmax.
// Only wave-private Ps (P^T transpose) remains in LDS.
// ============================================================
__global__ __launch_bounds__(256, 3) void attn(
    const unsigned short* __restrict__ Qp,
    const unsigned short* __restrict__ Kp,
    const unsigned short* __restrict__ Vt,
    const float* __restrict__ biasf,
    unsigned short* __restrict__ Oa) {
  __shared__ unsigned short Ps[4][16 * 72]; // per-wave P^T: [qrow][key]

  const int tid = threadIdx.x;
  const int w = tid >> 6, l = tid & 63;
  const int quad = l >> 4, l15 = l & 15;
  const int bid = blockIdx.x;
  const int bh = bid & 31;      // same bh -> same XCD (bid%8 == bh%8)
  const int qt = bid >> 5;      // 64 q-rows per block
  const int b = bh >> 3, h = bh & 7;
  const int qrow = qt * 64 + w * 16 + l15;

  // ---- Q fragments (B-operand of S^T), registers for whole kernel ----
  short8 aq[2];
#pragma unroll
  for (int k2 = 0; k2 < 2; ++k2)
    aq[k2] = *(const short8*)(Qp + ((size_t)bh * Qlen + qrow) * HDim + (k2 * 4 + quad) * 8);

  // lane-fixed base pointers for K/V fragment gathers
  const unsigned short* kptr = Kp + ((size_t)bh * Klen + l15) * HDim + quad * 8;
  const unsigned short* vptr = Vt + ((size_t)bh * HDim + l15) * Klen + quad * 8;
  const float* brow = biasf + b * Klen + quad * 4;

  // ---- prologue: K fragments for tile 0 ----
  short8 kf[8];
#pragma unroll
  for (int ct = 0; ct < 4; ++ct)
#pragma unroll
    for (int hf = 0; hf < 2; ++hf)
      kf[ct * 2 + hf] = *(const short8*)(kptr + (ct * 16) * HDim + hf * 32);

  f32x4 o[4] = {};                 // O^T: 16 d-values of q-row l15
  float m_run = -1.0e6f, l_acc = 0.f;
  constexpr float C1 = 0.125f * 1.4426950408889634f;  // scale*log2e
  constexpr int NT = Klen / 64;

  for (int kt = 0; kt < NT; ++kt) {
    // ---- V fragments for THIS tile (hidden behind S+softmax) ----
    short8 vf[8];
#pragma unroll
    for (int ctd = 0; ctd < 4; ++ctd)
#pragma unroll
      for (int hf = 0; hf < 2; ++hf)
        vf[ctd * 2 + hf] =
            *(const short8*)(vptr + (size_t)(ctd * 16) * Klen + kt * 64 + hf * 32);
    float4 bb[4];
#pragma unroll
    for (int ct = 0; ct < 4; ++ct)
      bb[ct] = *(const float4*)(brow + kt * 64 + ct * 16);

    // ---- S^T = K . Q^T : lane owns 16 scores of q-row l15 ----
    f32x4 sv[4];
#pragma unroll
    for (int ct = 0; ct < 4; ++ct) {
      f32x4 a = {};
      a = MFMA16(kf[ct * 2 + 0], aq[0], a);
      a = MFMA16(kf[ct * 2 + 1], aq[1], a);
      sv[ct] = a;
    }
    // ---- prefetch K fragments for NEXT tile (kf free after S) ----
    const int ktn = (kt + 1 < NT) ? kt + 1 : kt;
#pragma unroll
    for (int ct = 0; ct < 4; ++ct)
#pragma unroll
      for (int hf = 0; hf < 2; ++hf)
        kf[ct * 2 + hf] =
            *(const short8*)(kptr + (ktn * 64 + ct * 16) * HDim + hf * 32);

    // ---- per-lane softmax, exp2 domain ----
#pragma unroll
    for (int ct = 0; ct < 4; ++ct)
#pragma unroll
      for (int r = 0; r < 4; ++r)
        sv[ct][r] = sv[ct][r] * C1 + bb[ct][r];

    float mx0 = fmaxf(fmaxf(sv[0][0], sv[0][1]), fmaxf(sv[0][2], sv[0][3]));
    float mx1 = fmaxf(fmaxf(sv[1][0], sv[1][1]), fmaxf(sv[1][2], sv[1][3]));
    float mx2 = fmaxf(fmaxf(sv[2][0], sv[2][1]), fmaxf(sv[2][2], sv[2][3]));
    float mx3 = fmaxf(fmaxf(sv[3][0], sv[3][1]), fmaxf(sv[3][2], sv[3][3]));
    float mx = fmaxf(fmaxf(mx0, mx1), fmaxf(mx2, mx3));
    mx = fmaxf(mx, __shfl_xor(mx, 16));   // lanes sharing l15 (same q-row)
    mx = fmaxf(mx, __shfl_xor(mx, 32));
    float mnew  = fmaxf(m_run, mx);
    float alpha = exp2f(m_run - mnew);
    m_run = mnew;

    float ps = 0.f;
#pragma unroll
    for (int ct = 0; ct < 4; ++ct) {
      float p0 = exp2f(sv[ct][0] - mnew);
      float p1 = exp2f(sv[ct][1] - mnew);
      float p2 = exp2f(sv[ct][2] - mnew);
      float p3 = exp2f(sv[ct][3] - mnew);
      sv[ct][0] = p0; sv[ct][1] = p1; sv[ct][2] = p2; sv[ct][3] = p3;
      ps += (p0 + p1) + (p2 + p3);
    }
    l_acc = l_acc * alpha + ps;
#pragma unroll
    for (int ctd = 0; ctd < 4; ++ctd) o[ctd] *= alpha;

    // ---- P^T -> wave-private Ps (no barrier: same-wave LDS order) ----
#pragma unroll
    for (int ct = 0; ct < 4; ++ct) {
      unsigned pk[2] = {pk2h(sv[ct][0], sv[ct][1]), pk2h(sv[ct][2], sv[ct][3])};
      *(uint2*)&Ps[w][l15 * 72 + ct * 16 + quad * 4] = *(const uint2*)pk;
    }
    const short8 ap0 = *(const short8*)&Ps[w][l15 * 72 + quad * 8];        // keys 0..31
    const short8 ap1 = *(const short8*)&Ps[w][l15 * 72 + 32 + quad * 8];   // keys 32..63

    // ---- O^T += V^T . P^T ----
#pragma unroll
    for (int ctd = 0; ctd < 4; ++ctd) {
      o[ctd] = MFMA16(vf[ctd * 2 + 0], ap0, o[ctd]);
      o[ctd] = MFMA16(vf[ctd * 2 + 1], ap1, o[ctd]);
    }
  }

  // ---- epilogue ----
  float lt = l_acc;
  lt += __shfl_xor(lt, 16);
  lt += __shfl_xor(lt, 32);
  float rl = 1.0f / lt;
  const size_t obase = ((size_t)(b * Qlen) + qrow) * Dm + h * 64;
#pragma unroll
  for (int ctd = 0; ctd < 4; ++ctd) {
    unsigned pk[2] = {pk2h(o[ctd][0] * rl, o[ctd][1] * rl),
                      pk2h(o[ctd][2] * rl, o[ctd][3] * rl)};
    *(uint2*)(Oa + obase + ctd * 16 + quad * 4) = *(const uint2*)pk;
  }
}

extern "C" void kernel_launch(void* const* d_in, const int* in_sizes, int n_in,
                              void* d_out, int out_size, void* d_ws, size_t ws_size,
                              hipStream_t stream) {
  const float* q  = (const float*)d_in[0];
  const float* k  = (const float*)d_in[1];
  const float* v  = (const float*)d_in[2];
  const float* Wq = (const float*)d_in[3];
  const float* Wk = (const float*)d_in[4];
  const float* Wv = (const float*)d_in[5];
  const float* Wo = (const float*)d_in[6];
  const int*  msk = (const int*)d_in[7];
  float* out = (float*)d_out;

  char* ws = (char*)d_ws;
  const size_t SEG  = (size_t)Bc * Hh * Qlen * HDim * sizeof(unsigned short); // 8 MB
  const size_t WSEG = (size_t)Dm * Dm * sizeof(unsigned short);               // 0.5 MB
  unsigned short* Qp  = (unsigned short*)(ws);
  unsigned short* Kp  = (unsigned short*)(ws + SEG);
  unsigned short* Vp  = (unsigned short*)(ws + 2 * SEG);
  unsigned short* Vt  = (unsigned short*)(ws + 3 * SEG);
  unsigned short* Oa  = Vp;  // Vp dead after transpose_v; reuse for Oa
  unsigned short* Wqh = (unsigned short*)(ws + 4 * SEG);
  unsigned short* Wkh = (unsigned short*)(ws + 4 * SEG + WSEG);
  unsigned short* Wvh = (unsigned short*)(ws + 4 * SEG + 2 * WSEG);
  unsigned short* Woh = (unsigned short*)(ws + 4 * SEG + 3 * WSEG);
  float*          Bfs = (float*)(ws + 4 * SEG + 4 * WSEG);  // 32 KB bias
  unsigned short* qh  = (unsigned short*)(ws + 4 * SEG + 4 * WSEG + 65536);
  unsigned short* kh  = qh + SEG / 2;   // SEG bytes each (8 MB), elem counts
  unsigned short* vh  = kh + SEG / 2;
  const size_t NEED = 4 * SEG + 4 * WSEG + 65536 + 3 * SEG;
  const bool big = ws_size >= NEED;

  const int wn = Dm * Dm;                       // 262144
  hipLaunchKernelGGL(cvt4, dim3(wn / 1024, 5), dim3(256), 0, stream,
                     Wq, Wk, Wv, Wo, Wqh, Wkh, Wvh, Woh, msk, Bfs);

  if (big) {
    hipLaunchKernelGGL(cvt_in, dim3(4096, 3), dim3(256), 0, stream,
                       q, k, v, qh, kh, vh);
    hipLaunchKernelGGL(gemm_qkv<true>, dim3(64, 12), dim3(256), 0, stream,
                       q, k, v, qh, kh, vh, Wqh, Wkh, Wvh, Qp, Kp, Vp);
  } else {
    hipLaunchKernelGGL(gemm_qkv<false>, dim3(64, 12), dim3(256), 0, stream,
                       q, k, v, qh, kh, vh, Wqh, Wkh, Wvh, Qp, Kp, Vp);
  }
  hipLaunchKernelGGL(transpose_v, dim3(32, 32), dim3(256), 0, stream, Vp, Vt);
  hipLaunchKernelGGL(attn, dim3(1024), dim3(256), 0, stream, Qp, Kp, Vt, Bfs, Oa);
  hipLaunchKernelGGL(gemm_out, dim3(64, 4), dim3(256), 0, stream, Oa, Woh, out);
}

// Round 10
// 224.199 us; speedup vs baseline: 1.7242x; 1.7242x over previous
//
#include <hip/hip_runtime.h>

// ---- problem constants ----
constexpr int Bc   = 4;
constexpr int Qlen = 2048;
constexpr int Klen = 2048;
constexpr int Dm   = 512;
constexpr int Hh   = 8;
constexpr int HDim = 64;

typedef __attribute__((ext_vector_type(8))) short short8;       // 8x16-bit storage
typedef __attribute__((ext_vector_type(8))) _Float16 half8;     // fp16 MFMA frag
typedef __attribute__((ext_vector_type(2))) __fp16 fp16x2;      // cvt_pkrtz result
typedef __attribute__((ext_vector_type(4))) float f32x4;

__device__ __forceinline__ f32x4 MFMA16(short8 a, short8 b, f32x4 c) {
  return __builtin_amdgcn_mfma_f32_16x16x32_f16(
      __builtin_bit_cast(half8, a), __builtin_bit_cast(half8, b), c, 0, 0, 0);
}

__device__ __forceinline__ void gload_lds16(const void* g, void* l) {
  __builtin_amdgcn_global_load_lds(
      (const __attribute__((address_space(1))) void*)g,
      (__attribute__((address_space(3))) void*)l, 16, 0, 0);
}

__device__ __forceinline__ unsigned short f2h(float f) {
  _Float16 h = (_Float16)f;
  return __builtin_bit_cast(unsigned short, h);
}

__device__ __forceinline__ unsigned pk2h(float a, float b) {
  fp16x2 h = __builtin_amdgcn_cvt_pkrtz(a, b);
  return __builtin_bit_cast(unsigned, h);
}

// ============================================================
// cvt4: f32->fp16 of the 4 weight matrices + mask->f32 bias (seg 4)
// ============================================================
__global__ __launch_bounds__(256) void cvt4(
    const float* __restrict__ s0, const float* __restrict__ s1,
    const float* __restrict__ s2, const float* __restrict__ s3,
    unsigned short* __restrict__ o0, unsigned short* __restrict__ o1,
    unsigned short* __restrict__ o2, unsigned short* __restrict__ o3,
    const int* __restrict__ msk, float* __restrict__ biasf) {
  const int seg = blockIdx.y;
  int i = (blockIdx.x * 256 + threadIdx.x) * 4;
  if (seg < 4) {
    const float* s = (seg == 0) ? s0 : (seg == 1) ? s1 : (seg == 2) ? s2 : s3;
    unsigned short* o = (seg == 0) ? o0 : (seg == 1) ? o1 : (seg == 2) ? o2 : o3;
    float4 x = *(const float4*)(s + i);
    unsigned t[2] = {pk2h(x.x, x.y), pk2h(x.z, x.w)};
    *(uint2*)(o + i) = *(const uint2*)t;
  } else if (i + 3 < Bc * Klen) {
    int4 m = *(const int4*)(msk + i);
    float4 bo;
    bo.x = (m.x == 0) ? -60000.0f : 0.0f;
    bo.y = (m.y == 0) ? -60000.0f : 0.0f;
    bo.z = (m.z == 0) ? -60000.0f : 0.0f;
    bo.w = (m.w == 0) ? -60000.0f : 0.0f;
    *(float4*)(biasf + i) = bo;
  }
}

// ============================================================
// cvt_in: f32->fp16 of the 3 input activations
// ============================================================
__global__ __launch_bounds__(256) void cvt_in(
    const float* __restrict__ q, const float* __restrict__ k,
    const float* __restrict__ v,
    unsigned short* __restrict__ qh, unsigned short* __restrict__ kh,
    unsigned short* __restrict__ vh) {
  const int seg = blockIdx.y;
  const float* s = (seg == 0) ? q : (seg == 1) ? k : v;
  unsigned short* o = (seg == 0) ? qh : (seg == 1) ? kh : vh;
  int i = (blockIdx.x * 256 + threadIdx.x) * 4;
  float4 x = *(const float4*)(s + i);
  unsigned t[2] = {pk2h(x.x, x.y), pk2h(x.z, x.w)};
  *(uint2*)(o + i) = *(const uint2*)t;
}

// ============================================================
// Fused QKV projection
// ============================================================
template <bool F16A>
__global__ __launch_bounds__(256) void gemm_qkv(
    const float* __restrict__ q_in,
    const float* __restrict__ k_in,
    const float* __restrict__ v_in,
    const unsigned short* __restrict__ qh,
    const unsigned short* __restrict__ kh,
    const unsigned short* __restrict__ vh,
    const unsigned short* __restrict__ Wqh,
    const unsigned short* __restrict__ Wkh,
    const unsigned short* __restrict__ Wvh,
    unsigned short* __restrict__ Qp,
    unsigned short* __restrict__ Kp,
    unsigned short* __restrict__ Vp) {
  __shared__ unsigned short As[128 * 32];
  __shared__ unsigned short Bs[128 * 32];
  const int tid = threadIdx.x;
  const int w = tid >> 6, l = tid & 63;
  const int quad = l >> 4, l15 = l & 15;
  const int m0 = blockIdx.x * 128;
  const int n0 = blockIdx.y * 128;
  const int seg = n0 >> 9;
  const int f0  = n0 & 511;
  const float* Af = (seg == 0) ? q_in : (seg == 1) ? k_in : v_in;
  const unsigned short* Ah = (seg == 0) ? qh : (seg == 1) ? kh : vh;
  const unsigned short* W = (seg == 0) ? Wqh : (seg == 1) ? Wkh : Wvh;
  unsigned short* dst = (seg == 0) ? Qp : (seg == 1) ? Kp : Vp;

  f32x4 acc[4][4] = {};
  const int lrow = l >> 2;
  const int lcol = (l & 3) * 8;
  const int wm = (w >> 1) * 64, wn = (w & 1) * 64;

  for (int kk = 0; kk < 512; kk += 32) {
#pragma unroll
    for (int i = 0; i < 2; ++i) {
      int row = w * 32 + i * 16 + lrow;
      if constexpr (F16A) {
        gload_lds16(Ah + (size_t)(m0 + row) * 512 + kk + lcol, &As[row * 32 + lcol]);
      } else {
        const float* ap = Af + (size_t)(m0 + row) * 512 + kk + lcol;
        float4 x0 = *(const float4*)(ap);
        float4 x1 = *(const float4*)(ap + 4);
        unsigned t[4] = {pk2h(x0.x, x0.y), pk2h(x0.z, x0.w),
                         pk2h(x1.x, x1.y), pk2h(x1.z, x1.w)};
        *(uint4*)&As[row * 32 + lcol] = *(const uint4*)t;
      }
      gload_lds16(W + (size_t)(f0 + row) * 512 + kk + lcol, &Bs[row * 32 + lcol]);
    }
    __syncthreads();
    short8 af[4], bf[4];
#pragma unroll
    for (int t = 0; t < 4; ++t)
      af[t] = *(const short8*)&As[(wm + t * 16 + l15) * 32 + quad * 8];
#pragma unroll
    for (int t = 0; t < 4; ++t)
      bf[t] = *(const short8*)&Bs[(wn + t * 16 + l15) * 32 + quad * 8];
#pragma unroll
    for (int mt = 0; mt < 4; ++mt)
#pragma unroll
      for (int nt = 0; nt < 4; ++nt)
        acc[mt][nt] = MFMA16(af[mt], bf[nt], acc[mt][nt]);
    __syncthreads();
  }
#pragma unroll
  for (int mt = 0; mt < 4; ++mt)
#pragma unroll
    for (int nt = 0; nt < 4; ++nt)
#pragma unroll
      for (int r = 0; r < 4; ++r) {
        int m  = m0 + wm + mt * 16 + quad * 4 + r;
        int nn = f0 + wn + nt * 16 + l15;
        int b = m >> 11, qq = m & 2047;
        int h = nn >> 6, hd = nn & 63;
        dst[(((size_t)(b * Hh + h)) * Qlen + qq) * HDim + hd] = f2h(acc[mt][nt][r]);
      }
}

// ============================================================
// V transpose
// ============================================================
__global__ __launch_bounds__(256) void transpose_v(
    const unsigned short* __restrict__ Vp, unsigned short* __restrict__ Vt) {
  __shared__ unsigned short t[64 * 72];
  const int bh = blockIdx.y, jt = blockIdx.x;
  const int tid = threadIdx.x;
#pragma unroll
  for (int i = 0; i < 2; ++i) {
    int g = i * 256 + tid;
    int j = g >> 3, c8 = g & 7;
    *(uint4*)&t[j * 72 + c8 * 8] =
        *(const uint4*)(Vp + ((size_t)bh * Klen + jt * 64 + j) * 64 + c8 * 8);
  }
  __syncthreads();
#pragma unroll
  for (int i = 0; i < 2; ++i) {
    int g = i * 256 + tid;
    int d = g >> 3, j8 = g & 7;
    unsigned short tmp[8];
#pragma unroll
    for (int kx = 0; kx < 8; ++kx) tmp[kx] = t[(j8 * 8 + kx) * 72 + d];
    *(uint4*)(Vt + ((size_t)bh * HDim + d) * Klen + jt * 64 + j8 * 8) = *(const uint4*)tmp;
  }
}

// ============================================================
// Output projection
// ============================================================
__global__ __launch_bounds__(256) void gemm_out(
    const unsigned short* __restrict__ Oa,
    const unsigned short* __restrict__ Woh,
    float* __restrict__ out) {
  __shared__ unsigned short As[128 * 32];
  __shared__ unsigned short Bs[128 * 32];
  const int tid = threadIdx.x;
  const int w = tid >> 6, l = tid & 63;
  const int quad = l >> 4, l15 = l & 15;
  const int m0 = blockIdx.x * 128;
  const int n0 = blockIdx.y * 128;

  f32x4 acc[4][4] = {};
  const int lrow = l >> 2;
  const int lcol = (l & 3) * 8;
  const int wm = (w >> 1) * 64, wn = (w & 1) * 64;

  for (int kk = 0; kk < 512; kk += 32) {
#pragma unroll
    for (int i = 0; i < 2; ++i) {
      int row = w * 32 + i * 16 + lrow;
      gload_lds16(Oa + (size_t)(m0 + row) * 512 + kk + lcol, &As[row * 32 + lcol]);
      gload_lds16(Woh + (size_t)(n0 + row) * 512 + kk + lcol, &Bs[row * 32 + lcol]);
    }
    __syncthreads();
    short8 af[4], bf[4];
#pragma unroll
    for (int t = 0; t < 4; ++t)
      af[t] = *(const short8*)&As[(wm + t * 16 + l15) * 32 + quad * 8];
#pragma unroll
    for (int t = 0; t < 4; ++t)
      bf[t] = *(const short8*)&Bs[(wn + t * 16 + l15) * 32 + quad * 8];
#pragma unroll
    for (int mt = 0; mt < 4; ++mt)
#pragma unroll
      for (int nt = 0; nt < 4; ++nt)
        acc[mt][nt] = MFMA16(af[mt], bf[nt], acc[mt][nt]);
    __syncthreads();
  }
#pragma unroll
  for (int mt = 0; mt < 4; ++mt)
#pragma unroll
    for (int nt = 0; nt < 4; ++nt)
#pragma unroll
      for (int r = 0; r < 4; ++r) {
        int m  = m0 + wm + mt * 16 + quad * 4 + r;
        int nn = n0 + wn + nt * 16 + l15;
        out[(size_t)m * 512 + nn] = acc[mt][nt][r];
      }
}

// ============================================================
// Flash attention, r8 structure (LDS-staged K/V, transposed S^T
// geometry, per-lane softmax). KSPLIT: grid covers (bh, qt, part);
// each part covers Klen/2 keys, writes normalized partial O + the
// row logsumexp s = m + log2(l). SINGLE: full K, writes Oa direct.
// ============================================================
template <bool KSPLIT>
__global__ __launch_bounds__(256, 4) void attn(
    const unsigned short* __restrict__ Qp,
    const unsigned short* __restrict__ Kp,
    const unsigned short* __restrict__ Vt,
    const float* __restrict__ biasf,
    unsigned short* __restrict__ Oa,     // SINGLE: (B,Q,D) out
    unsigned short* __restrict__ Op,     // KSPLIT: partial O [part][bh][qrow][64]
    float* __restrict__ Sp) {            // KSPLIT: logsumexp [part][bh*Qlen]
  __shared__ unsigned short Ks[64 * 64];
  __shared__ unsigned short Vs[64 * 64];
  __shared__ unsigned short Ps[4][16 * 72];

  const int tid = threadIdx.x;
  const int w = tid >> 6, l = tid & 63;
  const int quad = l >> 4, l15 = l & 15;
  const int bid = blockIdx.x;
  const int bh = bid & 31;            // same bh -> same XCD
  int qt, part, kt0, ktN;
  if constexpr (KSPLIT) {
    int rest = bid >> 5;              // 0..63
    part = rest & 1;
    qt = rest >> 1;
    kt0 = part * 16; ktN = kt0 + 16;
  } else {
    part = 0; qt = bid >> 5; kt0 = 0; ktN = Klen / 64;
  }
  const int b = bh >> 3, h = bh & 7;
  const int x = l15 & 7;
  const int qrow = qt * 64 + w * 16 + l15;

  short8 aq[2];
#pragma unroll
  for (int k2 = 0; k2 < 2; ++k2)
    aq[k2] = *(const short8*)(Qp + ((size_t)bh * Qlen + qrow) * HDim + (k2 * 4 + quad) * 8);

  f32x4 o[4] = {};
  float m_run = -1.0e6f, l_acc = 0.f;
  constexpr float C1 = 0.125f * 1.4426950408889634f;
  const float* brow = biasf + b * Klen;

  for (int kt = kt0; kt < ktN; ++kt) {
    __syncthreads();
#pragma unroll
    for (int i = 0; i < 2; ++i) {
      int g = i * 256 + tid;
      int row = g >> 3, c8 = g & 7;
      int sb = (c8 ^ (row & 7)) * 8;
      gload_lds16(Kp + ((size_t)bh * Klen + kt * 64 + row) * HDim + sb, &Ks[g * 8]);
      gload_lds16(Vt + ((size_t)bh * HDim + row) * Klen + kt * 64 + sb, &Vs[g * 8]);
    }
    float4 bb[4];
#pragma unroll
    for (int ct = 0; ct < 4; ++ct)
      bb[ct] = *(const float4*)(brow + kt * 64 + ct * 16 + quad * 4);
    __syncthreads();

    // ---- S^T = K . Q^T ----
    f32x4 sv[4];
#pragma unroll
    for (int ct = 0; ct < 4; ++ct) {
      const short8 bk0 = *(const short8*)&Ks[(ct * 16 + l15) * 64 + (quad ^ x) * 8];
      const short8 bk1 = *(const short8*)&Ks[(ct * 16 + l15) * 64 + ((4 + quad) ^ x) * 8];
      f32x4 a = {};
      a = MFMA16(bk0, aq[0], a);
      a = MFMA16(bk1, aq[1], a);
      sv[ct] = a;
    }

    // ---- per-lane softmax, exp2 domain ----
#pragma unroll
    for (int ct = 0; ct < 4; ++ct)
#pragma unroll
      for (int r = 0; r < 4; ++r)
        sv[ct][r] = sv[ct][r] * C1 + bb[ct][r];

    float mx0 = fmaxf(fmaxf(sv[0][0], sv[0][1]), fmaxf(sv[0][2], sv[0][3]));
    float mx1 = fmaxf(fmaxf(sv[1][0], sv[1][1]), fmaxf(sv[1][2], sv[1][3]));
    float mx2 = fmaxf(fmaxf(sv[2][0], sv[2][1]), fmaxf(sv[2][2], sv[2][3]));
    float mx3 = fmaxf(fmaxf(sv[3][0], sv[3][1]), fmaxf(sv[3][2], sv[3][3]));
    float mx = fmaxf(fmaxf(mx0, mx1), fmaxf(mx2, mx3));
    mx = fmaxf(mx, __shfl_xor(mx, 16));
    mx = fmaxf(mx, __shfl_xor(mx, 32));
    float mnew  = fmaxf(m_run, mx);
    float alpha = exp2f(m_run - mnew);
    m_run = mnew;

    float ps = 0.f;
#pragma unroll
    for (int ct = 0; ct < 4; ++ct) {
      float p0 = exp2f(sv[ct][0] - mnew);
      float p1 = exp2f(sv[ct][1] - mnew);
      float p2 = exp2f(sv[ct][2] - mnew);
      float p3 = exp2f(sv[ct][3] - mnew);
      sv[ct][0] = p0; sv[ct][1] = p1; sv[ct][2] = p2; sv[ct][3] = p3;
      ps += (p0 + p1) + (p2 + p3);
    }
    l_acc = l_acc * alpha + ps;
#pragma unroll
    for (int ctd = 0; ctd < 4; ++ctd) o[ctd] *= alpha;

    // ---- P^T -> wave-private Ps ----
#pragma unroll
    for (int ct = 0; ct < 4; ++ct) {
      unsigned pk[2] = {pk2h(sv[ct][0], sv[ct][1]), pk2h(sv[ct][2], sv[ct][3])};
      *(uint2*)&Ps[w][l15 * 72 + ct * 16 + quad * 4] = *(const uint2*)pk;
    }
    const short8 ap0 = *(const short8*)&Ps[w][l15 * 72 + quad * 8];
    const short8 ap1 = *(const short8*)&Ps[w][l15 * 72 + 32 + quad * 8];

    // ---- O^T += V^T . P^T ----
#pragma unroll
    for (int ctd = 0; ctd < 4; ++ctd) {
      const short8 bv0 = *(const short8*)&Vs[(ctd * 16 + l15) * 64 + (quad ^ x) * 8];
      const short8 bv1 = *(const short8*)&Vs[(ctd * 16 + l15) * 64 + ((4 + quad) ^ x) * 8];
      o[ctd] = MFMA16(bv0, ap0, o[ctd]);
      o[ctd] = MFMA16(bv1, ap1, o[ctd]);
    }
  }

  // ---- epilogue ----
  float lt = l_acc;
  lt += __shfl_xor(lt, 16);
  lt += __shfl_xor(lt, 32);
  float rl = 1.0f / lt;
  if constexpr (KSPLIT) {
    const size_t pbase = ((size_t)part * 32 + bh) * Qlen;  // rows of this part
    const size_t obase = (pbase + qrow) * 64;
#pragma unroll
    for (int ctd = 0; ctd < 4; ++ctd) {
      unsigned pk[2] = {pk2h(o[ctd][0] * rl, o[ctd][1] * rl),
                        pk2h(o[ctd][2] * rl, o[ctd][3] * rl)};
      *(uint2*)(Op + obase + ctd * 16 + quad * 4) = *(const uint2*)pk;
    }
    if (l < 16)  // one lane per q-row (quad==0)
      Sp[pbase + qrow] = m_run + log2f(lt);
  } else {
    const size_t obase = ((size_t)(b * Qlen) + qrow) * Dm + h * 64;
#pragma unroll
    for (int ctd = 0; ctd < 4; ++ctd) {
      unsigned pk[2] = {pk2h(o[ctd][0] * rl, o[ctd][1] * rl),
                        pk2h(o[ctd][2] * rl, o[ctd][3] * rl)};
      *(uint2*)(Oa + obase + ctd * 16 + quad * 4) = *(const uint2*)pk;
    }
  }
}

// ============================================================
// reduce_o: combine the 2 K-split partials -> Oa (B,Q,D) fp16
// ============================================================
__global__ __launch_bounds__(256) void reduce_o(
    const unsigned short* __restrict__ Op, const float* __restrict__ Sp,
    unsigned short* __restrict__ Oa) {
  int g = blockIdx.x * 256 + threadIdx.x;
  int row = g >> 3, c8 = g & 7;              // row = bh*Qlen + qrow
  const size_t PART = (size_t)32 * Qlen;     // rows per part
  float s1 = Sp[row], s2 = Sp[PART + row];
  float M = fmaxf(s1, s2);
  float w1 = exp2f(s1 - M), w2 = exp2f(s2 - M);
  float rs = 1.0f / (w1 + w2);
  w1 *= rs; w2 *= rs;
  short8 a = *(const short8*)(Op + (size_t)row * 64 + c8 * 8);
  short8 bvec = *(const short8*)(Op + (PART + row) * 64 + c8 * 8);
  half8 af = __builtin_bit_cast(half8, a);
  half8 bf = __builtin_bit_cast(half8, bvec);
  unsigned pk[4];
#pragma unroll
  for (int i = 0; i < 4; ++i) {
    float r0 = w1 * (float)af[i * 2 + 0] + w2 * (float)bf[i * 2 + 0];
    float r1 = w1 * (float)af[i * 2 + 1] + w2 * (float)bf[i * 2 + 1];
    pk[i] = pk2h(r0, r1);
  }
  int bh = row >> 11, qrow = row & 2047;
  int b = bh >> 3, h = bh & 7;
  *(uint4*)(Oa + ((size_t)(b * Qlen) + qrow) * Dm + h * 64 + c8 * 8) =
      *(const uint4*)pk;
}

extern "C" void kernel_launch(void* const* d_in, const int* in_sizes, int n_in,
                              void* d_out, int out_size, void* d_ws, size_t ws_size,
                              hipStream_t stream) {
  const float* q  = (const float*)d_in[0];
  const float* k  = (const float*)d_in[1];
  const float* v  = (const float*)d_in[2];
  const float* Wq = (const float*)d_in[3];
  const float* Wk = (const float*)d_in[4];
  const float* Wv = (const float*)d_in[5];
  const float* Wo = (const float*)d_in[6];
  const int*  msk = (const int*)d_in[7];
  float* out = (float*)d_out;

  char* ws = (char*)d_ws;
  const size_t SEG  = (size_t)Bc * Hh * Qlen * HDim * sizeof(unsigned short); // 8 MB
  const size_t WSEG = (size_t)Dm * Dm * sizeof(unsigned short);               // 0.5 MB
  unsigned short* Qp  = (unsigned short*)(ws);
  unsigned short* Kp  = (unsigned short*)(ws + SEG);
  unsigned short* Vp  = (unsigned short*)(ws + 2 * SEG);
  unsigned short* Vt  = (unsigned short*)(ws + 3 * SEG);
  unsigned short* Oa  = Vp;  // Vp dead after transpose_v
  unsigned short* Wqh = (unsigned short*)(ws + 4 * SEG);
  unsigned short* Wkh = (unsigned short*)(ws + 4 * SEG + WSEG);
  unsigned short* Wvh = (unsigned short*)(ws + 4 * SEG + 2 * WSEG);
  unsigned short* Woh = (unsigned short*)(ws + 4 * SEG + 3 * WSEG);
  float*          Bfs = (float*)(ws + 4 * SEG + 4 * WSEG);  // 32 KB bias
  unsigned short* qh  = (unsigned short*)(ws + 4 * SEG + 4 * WSEG + 65536);
  unsigned short* kh  = qh + SEG / 2;
  unsigned short* vh  = kh + SEG / 2;
  // K-split partials alias qh/kh (dead after gemm_qkv); Sp aliases vh.
  unsigned short* Op  = qh;                  // 2 parts x 8 MB
  float*          Sp  = (float*)vh;          // 2 x 64K floats = 512 KB
  const size_t NEED = 4 * SEG + 4 * WSEG + 65536 + 3 * SEG;
  const bool big = ws_size >= NEED;

  const int wn = Dm * Dm;
  hipLaunchKernelGGL(cvt4, dim3(wn / 1024, 5), dim3(256), 0, stream,
                     Wq, Wk, Wv, Wo, Wqh, Wkh, Wvh, Woh, msk, Bfs);

  if (big) {
    hipLaunchKernelGGL(cvt_in, dim3(4096, 3), dim3(256), 0, stream,
                       q, k, v, qh, kh, vh);
    hipLaunchKernelGGL(gemm_qkv<true>, dim3(64, 12), dim3(256), 0, stream,
                       q, k, v, qh, kh, vh, Wqh, Wkh, Wvh, Qp, Kp, Vp);
    hipLaunchKernelGGL(transpose_v, dim3(32, 32), dim3(256), 0, stream, Vp, Vt);
    hipLaunchKernelGGL(attn<true>, dim3(2048), dim3(256), 0, stream,
                       Qp, Kp, Vt, Bfs, Oa, Op, Sp);
    hipLaunchKernelGGL(reduce_o, dim3(2048), dim3(256), 0, stream, Op, Sp, Oa);
  } else {
    hipLaunchKernelGGL(gemm_qkv<false>, dim3(64, 12), dim3(256), 0, stream,
                       q, k, v, qh, kh, vh, Wqh, Wkh, Wvh, Qp, Kp, Vp);
    hipLaunchKernelGGL(transpose_v, dim3(32, 32), dim3(256), 0, stream, Vp, Vt);
    hipLaunchKernelGGL(attn<false>, dim3(1024), dim3(256), 0, stream,
                       Qp, Kp, Vt, Bfs, Oa, Op, Sp);
  }
  hipLaunchKernelGGL(gemm_out, dim3(64, 4), dim3(256), 0, stream, Oa, Woh, out);
}